// Round 12
// baseline (94.311 us; speedup 1.0000x reference)
//
#include <hip/hip_runtime.h>

#define E_TOT 320000
#define NN    10000
#define DN    128
#define DE    32
#define DH    192
#define DO    128
#define EB    32    // edges per block (128 threads = 2 waves)
#define SHS   196   // s_h row stride in ushorts (392 B)
#define SMT   36    // s_msgT row stride in ushorts (72 B, 8B-aligned)

typedef __attribute__((ext_vector_type(8))) short bf16x8;
typedef __attribute__((ext_vector_type(4))) float f32x4;

// packed weight tables (rewritten every launch)
#define W1_FRAGS (8*12*64)    // node-part B-frags (node_proj)
#define E_FRAGS  (12*64)      // W1_edge^T A-frags (edge GEMM1)
#define W2_FRAGS (6*8*64)     // W2 B-frags
#define FRAGS_TOT (W1_FRAGS + E_FRAGS + W2_FRAGS)
__device__ __align__(16) unsigned short g_p1[W1_FRAGS * 8];
__device__ __align__(16) unsigned short g_e [E_FRAGS * 8];
__device__ __align__(16) unsigned short g_p2[W2_FRAGS * 8];

__device__ __forceinline__ unsigned short f2bf(float f) {
    union { float f; unsigned u; } v; v.f = f;
    return (unsigned short)((v.u + 0x7FFFu + ((v.u >> 16) & 1u)) >> 16);
}
__device__ __forceinline__ float bflo(unsigned u) {
    union { unsigned v; float f; } t; t.v = u << 16; return t.f;
}
__device__ __forceinline__ float bfhi(unsigned u) {
    union { unsigned v; float f; } t; t.v = u & 0xFFFF0000u; return t.f;
}
__device__ __forceinline__ float bf2f(unsigned short s) {
    union { unsigned v; float f; } t; t.v = (unsigned)s << 16; return t.f;
}
__device__ __forceinline__ float tanh_fast(float x) {
    float ex = __expf(x + x);
    return 1.0f - 2.0f * __builtin_amdgcn_rcpf(ex + 1.0f);
}
__device__ __forceinline__ unsigned cvt_pk_bf16(float lo, float hi) {
    unsigned r;
    asm("v_cvt_pk_bf16_f32 %0, %1, %2" : "=v"(r) : "v"(lo), "v"(hi));
    return r;
}

// ---------------------------------------------------------------------------
// prep: pack weight tables + per-node 1/count table (out zeroed by memset)
// ---------------------------------------------------------------------------
__global__ void prep(const float* __restrict__ W1, const float* __restrict__ W2,
                     const int* __restrict__ senders, float* __restrict__ invc)
{
    int f = blockIdx.x * 256 + threadIdx.x;
    unsigned short tmp[8];
    if (f < W1_FRAGS) {                       // node-part B-frags: rows 0..255 of W1
        int kk = f / (12 * 64), nt = (f >> 6) % 12, lane = f & 63;
        int r0 = kk * 32 + ((lane >> 4) << 3);
        int c  = nt * 16 + (lane & 15);
        #pragma unroll
        for (int i = 0; i < 8; ++i) tmp[i] = f2bf(W1[(r0 + i) * DH + c]);
        *(uint4*)(g_p1 + (size_t)f * 8) = *(const uint4*)tmp;
    } else if (f < W1_FRAGS + E_FRAGS) {      // W1_edge^T A-frags
        int f2 = f - W1_FRAGS;
        int mt = f2 >> 6, lane = f2 & 63;
        int k0 = ((lane >> 4) << 3);
        int hid = mt * 16 + (lane & 15);
        #pragma unroll
        for (int i = 0; i < 8; ++i) tmp[i] = f2bf(W1[(256 + k0 + i) * DH + hid]);
        *(uint4*)(g_e + (size_t)f2 * 8) = *(const uint4*)tmp;
    } else if (f < FRAGS_TOT) {               // W2 B-frags
        int f3 = f - W1_FRAGS - E_FRAGS;
        int kk = f3 / (8 * 64), nt = (f3 >> 6) % 8, lane = f3 & 63;
        int r0 = kk * 32 + ((lane >> 4) << 3);
        int c  = nt * 16 + (lane & 15);
        #pragma unroll
        for (int i = 0; i < 8; ++i) tmp[i] = f2bf(W2[(r0 + i) * DO + c]);
        *(uint4*)(g_p2 + (size_t)f3 * 8) = *(const uint4*)tmp;
    } else if (f < FRAGS_TOT + NN) {
        int n = f - FRAGS_TOT;
        int lo = 0, hi = E_TOT;
        while (lo < hi) { int m = (lo + hi) >> 1; if (senders[m] < n) lo = m + 1; else hi = m; }
        int s0 = lo;
        hi = E_TOT;
        while (lo < hi) { int m = (lo + hi) >> 1; if (senders[m] < n + 1) lo = m + 1; else hi = m; }
        int cnt = lo - s0;
        invc[n] = (cnt > 1) ? 1.0f / (float)cnt : 1.0f;
    }
}

// ---------------------------------------------------------------------------
// node projections (lane-contiguous P' layout):
//   P'[n][g][mt][i]: addr = (n*4+g)*48 + mt*4 + i;  original col = mt*16+g*4+i
// ---------------------------------------------------------------------------
__global__ __launch_bounds__(256) void node_proj(
    const float* __restrict__ n_embed, const float* __restrict__ b1,
    unsigned short* __restrict__ P)
{
    __shared__ __align__(16) unsigned short s_a[64][136];
    const int tid  = threadIdx.x;
    const int half = blockIdx.y;
    const int n0   = blockIdx.x * 64;

    #pragma unroll
    for (int it = 0; it < 8; ++it) {
        int idx = tid + it * 256;
        int row = idx >> 5, c = idx & 31;
        float4 v = make_float4(0.f, 0.f, 0.f, 0.f);
        if (n0 + row < NN) v = ((const float4*)(n_embed + (size_t)(n0 + row) * DN))[c];
        unsigned t0 = cvt_pk_bf16(v.x, v.y), t1 = cvt_pk_bf16(v.z, v.w);
        *(uint2*)&s_a[row][c * 4] = make_uint2(t0, t1);
    }
    __syncthreads();

    const int lane = tid & 63, w = tid >> 6;
    const int arow = lane & 15, akb = (lane >> 4) * 8, rbase = (lane >> 4) * 4;

    f32x4 acc[4][3];
    #pragma unroll
    for (int mt = 0; mt < 4; ++mt)
        #pragma unroll
        for (int j = 0; j < 3; ++j) acc[mt][j] = (f32x4){0.f, 0.f, 0.f, 0.f};

    for (int kk = 0; kk < 4; ++kk) {
        bf16x8 a[4], b[3];
        #pragma unroll
        for (int mt = 0; mt < 4; ++mt)
            a[mt] = *(const bf16x8*)&s_a[mt * 16 + arow][kk * 32 + akb];
        #pragma unroll
        for (int j = 0; j < 3; ++j)
            b[j] = *(const bf16x8*)(g_p1 + (((size_t)(kk + 4 * half) * 12 + (3 * w + j)) * 64 + lane) * 8);
        #pragma unroll
        for (int mt = 0; mt < 4; ++mt)
            #pragma unroll
            for (int j = 0; j < 3; ++j)
                acc[mt][j] = __builtin_amdgcn_mfma_f32_16x16x32_bf16(a[mt], b[j], acc[mt][j], 0, 0, 0);
    }

    unsigned short* Pout = P + (size_t)half * NN * DH;
    float bj[3];
    #pragma unroll
    for (int j = 0; j < 3; ++j) bj[j] = (half == 0) ? b1[48 * w + 16 * j + arow] : 0.f;
    const int gq = arow >> 2, ii = arow & 3;
    #pragma unroll
    for (int mt = 0; mt < 4; ++mt)
        #pragma unroll
        for (int j = 0; j < 3; ++j)
            #pragma unroll
            for (int r = 0; r < 4; ++r) {
                int row = n0 + mt * 16 + rbase + r;
                if (row < NN)
                    Pout[((size_t)row * 4 + gq) * 48 + (3 * w + j) * 4 + ii] =
                        f2bf(acc[mt][j][r] + bj[j]);
            }
}

// ---------------------------------------------------------------------------
// fused edge kernel, 128 threads / 2 waves / 32 edges:
//   LDS ~12.7 KB -> 12 blocks/CU (24 waves, 75% ceiling; was 4-6 blocks).
//   Same per-edge math as R9; GEMM2 j-tiles 4 per wave (was 2).
// ---------------------------------------------------------------------------
__global__ __launch_bounds__(128) void edge_mlp11(
    const float* __restrict__ e_embed,
    const int* __restrict__ senders, const int* __restrict__ receivers,
    const unsigned short* __restrict__ Ps, const unsigned short* __restrict__ Pr,
    const float* __restrict__ b2, const float* __restrict__ invc,
    float* __restrict__ out)
{
    __shared__ __align__(16) char s_u[EB * SHS * 2];       // 12544 B (union)
    __shared__ int s_send[EB];
    unsigned short (*s_h)[SHS]    = (unsigned short(*)[SHS])s_u;  // [32][196]
    unsigned short (*s_msgT)[SMT] = (unsigned short(*)[SMT])s_u;  // [128][36] = 9216 B

    const int tid  = threadIdx.x;
    const int nb8  = gridDim.x >> 3;                       // 1250
    const int e0   = (((blockIdx.x & 7) * nb8) + (blockIdx.x >> 3)) * EB;  // XCD swizzle
    const int lane = tid & 63, w = tid >> 6;               // w in {0,1}
    const int arow = lane & 15, g = lane >> 4;

    // ---- phase 0: per-lane loads (wide, contiguous per lane) ----
    const int myedge = e0 + w * 16 + arow;
    const int sN = senders[myedge], rN = receivers[myedge];
    const unsigned short* psbase = Ps + ((size_t)sN * 4 + g) * 48;
    const unsigned short* prbase = Pr + ((size_t)rN * 4 + g) * 48;
    uint4 psq[6], prq[6];
    #pragma unroll
    for (int j = 0; j < 6; ++j) {
        psq[j] = *(const uint4*)(psbase + j * 8);
        prq[j] = *(const uint4*)(prbase + j * 8);
    }
    union { bf16x8 v; unsigned u[4]; } bfr;
    {
        const float* erow = e_embed + (size_t)myedge * DE + g * 8;
        float4 ev0 = *(const float4*)erow;
        float4 ev1 = *(const float4*)(erow + 4);
        bfr.u[0] = cvt_pk_bf16(ev0.x, ev0.y);
        bfr.u[1] = cvt_pk_bf16(ev0.z, ev0.w);
        bfr.u[2] = cvt_pk_bf16(ev1.x, ev1.y);
        bfr.u[3] = cvt_pk_bf16(ev1.z, ev1.w);
    }
    if (tid < EB) s_send[tid] = senders[e0 + tid];

    // ---- phase 1: GEMM1^T (12 MFMAs) + P add + tanh -> s_h[edge][hid] ----
    #pragma unroll
    for (int mt = 0; mt < 12; ++mt) {
        unsigned px, py, qx, qy;
        if ((mt & 1) == 0) {
            px = psq[mt >> 1].x; py = psq[mt >> 1].y;
            qx = prq[mt >> 1].x; qy = prq[mt >> 1].y;
        } else {
            px = psq[mt >> 1].z; py = psq[mt >> 1].w;
            qx = prq[mt >> 1].z; qy = prq[mt >> 1].w;
        }
        bf16x8 af = *(const bf16x8*)(g_e + ((size_t)mt * 64 + lane) * 8);
        f32x4 z = (f32x4){0.f, 0.f, 0.f, 0.f};
        f32x4 acc = __builtin_amdgcn_mfma_f32_16x16x32_bf16(af, bfr.v, z, 0, 0, 0);
        float t0 = tanh_fast(acc[0] + bflo(px) + bflo(qx));
        float t1 = tanh_fast(acc[1] + bfhi(px) + bfhi(qx));
        float t2 = tanh_fast(acc[2] + bflo(py) + bflo(qy));
        float t3 = tanh_fast(acc[3] + bfhi(py) + bfhi(qy));
        *(uint2*)&s_h[w * 16 + arow][mt * 16 + g * 4] =
            make_uint2(cvt_pk_bf16(t0, t1), cvt_pk_bf16(t2, t3));
    }
    __syncthreads();

    // ---- phase 2: GEMM2  msg = h @ W2  (2 m-tiles x 4 j-tiles per wave) ----
    f32x4 acc2[2][4];
    #pragma unroll
    for (int mt = 0; mt < 2; ++mt)
        #pragma unroll
        for (int j = 0; j < 4; ++j) acc2[mt][j] = (f32x4){0.f, 0.f, 0.f, 0.f};

    #pragma unroll
    for (int kk = 0; kk < 6; ++kk) {
        union { bf16x8 v; uint2 p[2]; } a[2];
        bf16x8 b[4];
        #pragma unroll
        for (int mt = 0; mt < 2; ++mt) {
            const unsigned short* hp = &s_h[mt * 16 + arow][kk * 32 + g * 8];
            a[mt].p[0] = *(const uint2*)hp;
            a[mt].p[1] = *(const uint2*)(hp + 4);
        }
        #pragma unroll
        for (int j = 0; j < 4; ++j)
            b[j] = *(const bf16x8*)(g_p2 + (((size_t)kk * 8 + (4 * w + j)) * 64 + lane) * 8);
        #pragma unroll
        for (int mt = 0; mt < 2; ++mt)
            #pragma unroll
            for (int j = 0; j < 4; ++j)
                acc2[mt][j] = __builtin_amdgcn_mfma_f32_16x16x32_bf16(a[mt].v, b[j], acc2[mt][j], 0, 0, 0);
    }
    __syncthreads();   // all s_h reads done before s_msgT overwrites the union

    // ---- phase 3: bf16 transposed spill  s_msgT[col][edge], bias added first ----
    #pragma unroll
    for (int j = 0; j < 4; ++j) {
        const float bd = b2[64 * w + 16 * j + arow];
        #pragma unroll
        for (int mt = 0; mt < 2; ++mt) {
            float v0 = acc2[mt][j][0] + bd, v1 = acc2[mt][j][1] + bd;
            float v2 = acc2[mt][j][2] + bd, v3 = acc2[mt][j][3] + bd;
            *(uint2*)&s_msgT[64 * w + 16 * j + arow][mt * 16 + g * 4] =
                make_uint2(cvt_pk_bf16(v0, v1), cvt_pk_bf16(v2, v3));
        }
    }
    __syncthreads();

    // ---- phase 4: per-column segment reduce (sorted senders), scaled flush ----
    {
        const int c = tid;                     // 128 threads = 128 cols
        float vals[32];
        #pragma unroll
        for (int k = 0; k < 8; ++k) {
            uint2 v = *(const uint2*)&s_msgT[c][k * 4];
            vals[k * 4 + 0] = bflo(v.x); vals[k * 4 + 1] = bfhi(v.x);
            vals[k * 4 + 2] = bflo(v.y); vals[k * 4 + 3] = bfhi(v.y);
        }
        float sum = 0.f;
        int cur = s_send[0];
        #pragma unroll
        for (int e = 0; e < 32; ++e) {
            sum += vals[e];
            int nxt = (e + 1 < 32) ? s_send[e + 1] : -1;
            if (nxt != cur) {
                atomicAdd(&out[(size_t)cur * DO + c], sum * invc[cur]);
                sum = 0.f;
                cur = nxt;
            }
        }
    }
}

extern "C" void kernel_launch(void* const* d_in, const int* in_sizes, int n_in,
                              void* d_out, int out_size, void* d_ws, size_t ws_size,
                              hipStream_t stream)
{
    const float* n_embed   = (const float*)d_in[0];
    const float* e_embed   = (const float*)d_in[1];
    const int*   senders   = (const int*)d_in[2];
    const int*   receivers = (const int*)d_in[3];
    const float* W1        = (const float*)d_in[4];
    const float* b1        = (const float*)d_in[5];
    const float* W2        = (const float*)d_in[6];
    const float* b2        = (const float*)d_in[7];
    float* out = (float*)d_out;

    unsigned short* Ps = (unsigned short*)d_ws;             // [NN][192] bf16 (lane-packed)
    unsigned short* Pr = Ps + (size_t)NN * DH;              // [NN][192] bf16 (lane-packed)
    float*          invc = (float*)(Pr + (size_t)NN * DH);  // [NN] f32

    hipMemsetAsync(out, 0, (size_t)NN * DO * sizeof(float), stream);
    const int prep_items = FRAGS_TOT + NN;
    prep<<<(prep_items + 255) / 256, 256, 0, stream>>>(W1, W2, senders, invc);
    node_proj<<<dim3((NN + 63) / 64, 2), 256, 0, stream>>>(n_embed, b1, Ps);
    edge_mlp11<<<E_TOT / EB, 128, 0, stream>>>(
        e_embed, senders, receivers, Ps, Pr, b2, invc, out);
}

// Round 13
// 93.932 us; speedup vs baseline: 1.0040x; 1.0040x over previous
//
#include <hip/hip_runtime.h>

#define E_TOT 320000
#define NN    10000
#define DN    128
#define DE    32
#define DH    192
#define DO    128
#define EB    64
#define SHS   196   // s_h row stride in ushorts (392 B)

typedef __attribute__((ext_vector_type(8))) short bf16x8;
typedef __attribute__((ext_vector_type(4))) float f32x4;

// packed weight tables (rewritten every launch)
#define W1_FRAGS (8*12*64)    // node-part B-frags (node_proj)
#define E_FRAGS  (12*64)      // W1_edge^T A-frags (edge GEMM1)
#define W2_FRAGS (6*8*64)     // W2 B-frags (node_out)
#define FRAGS_TOT (W1_FRAGS + E_FRAGS + W2_FRAGS)
__device__ __align__(16) unsigned short g_p1[W1_FRAGS * 8];
__device__ __align__(16) unsigned short g_e [E_FRAGS * 8];
__device__ __align__(16) unsigned short g_p2[W2_FRAGS * 8];

__device__ __forceinline__ unsigned short f2bf(float f) {
    union { float f; unsigned u; } v; v.f = f;
    return (unsigned short)((v.u + 0x7FFFu + ((v.u >> 16) & 1u)) >> 16);
}
__device__ __forceinline__ float bflo(unsigned u) {
    union { unsigned v; float f; } t; t.v = u << 16; return t.f;
}
__device__ __forceinline__ float bfhi(unsigned u) {
    union { unsigned v; float f; } t; t.v = u & 0xFFFF0000u; return t.f;
}
__device__ __forceinline__ float bf2f(unsigned short s) {
    union { unsigned v; float f; } t; t.v = (unsigned)s << 16; return t.f;
}
__device__ __forceinline__ float tanh_fast(float x) {
    float ex = __expf(x + x);
    return 1.0f - 2.0f * __builtin_amdgcn_rcpf(ex + 1.0f);
}
__device__ __forceinline__ unsigned cvt_pk_bf16(float lo, float hi) {
    unsigned r;
    asm("v_cvt_pk_bf16_f32 %0, %1, %2" : "=v"(r) : "v"(lo), "v"(hi));
    return r;
}

// ---------------------------------------------------------------------------
// prep: pack weight tables + per-node 1/count (0 for empty nodes)
// ---------------------------------------------------------------------------
__global__ void prep(const float* __restrict__ W1, const float* __restrict__ W2,
                     const int* __restrict__ senders, float* __restrict__ invc)
{
    int f = blockIdx.x * 256 + threadIdx.x;
    unsigned short tmp[8];
    if (f < W1_FRAGS) {                       // node-part B-frags: rows 0..255 of W1
        int kk = f / (12 * 64), nt = (f >> 6) % 12, lane = f & 63;
        int r0 = kk * 32 + ((lane >> 4) << 3);
        int c  = nt * 16 + (lane & 15);
        #pragma unroll
        for (int i = 0; i < 8; ++i) tmp[i] = f2bf(W1[(r0 + i) * DH + c]);
        *(uint4*)(g_p1 + (size_t)f * 8) = *(const uint4*)tmp;
    } else if (f < W1_FRAGS + E_FRAGS) {      // W1_edge^T A-frags
        int f2 = f - W1_FRAGS;
        int mt = f2 >> 6, lane = f2 & 63;
        int k0 = ((lane >> 4) << 3);
        int hid = mt * 16 + (lane & 15);
        #pragma unroll
        for (int i = 0; i < 8; ++i) tmp[i] = f2bf(W1[(256 + k0 + i) * DH + hid]);
        *(uint4*)(g_e + (size_t)f2 * 8) = *(const uint4*)tmp;
    } else if (f < FRAGS_TOT) {               // W2 B-frags
        int f3 = f - W1_FRAGS - E_FRAGS;
        int kk = f3 / (8 * 64), nt = (f3 >> 6) % 8, lane = f3 & 63;
        int r0 = kk * 32 + ((lane >> 4) << 3);
        int c  = nt * 16 + (lane & 15);
        #pragma unroll
        for (int i = 0; i < 8; ++i) tmp[i] = f2bf(W2[(r0 + i) * DO + c]);
        *(uint4*)(g_p2 + (size_t)f3 * 8) = *(const uint4*)tmp;
    } else if (f < FRAGS_TOT + NN) {
        int n = f - FRAGS_TOT;
        int lo = 0, hi = E_TOT;
        while (lo < hi) { int m = (lo + hi) >> 1; if (senders[m] < n) lo = m + 1; else hi = m; }
        int s0 = lo;
        hi = E_TOT;
        while (lo < hi) { int m = (lo + hi) >> 1; if (senders[m] < n + 1) lo = m + 1; else hi = m; }
        int cnt = lo - s0;
        invc[n] = (cnt > 0) ? 1.0f / (float)cnt : 0.0f;
    }
}

// ---------------------------------------------------------------------------
// node projections (= R9's, lane-contiguous P' layout):
//   P'[n][g][mt][i]: addr = (n*4+g)*48 + mt*4 + i;  original col = mt*16+g*4+i
// ---------------------------------------------------------------------------
__global__ __launch_bounds__(256) void node_proj(
    const float* __restrict__ n_embed, const float* __restrict__ b1,
    unsigned short* __restrict__ P)
{
    __shared__ __align__(16) unsigned short s_a[64][136];
    const int tid  = threadIdx.x;
    const int half = blockIdx.y;
    const int n0   = blockIdx.x * 64;

    #pragma unroll
    for (int it = 0; it < 8; ++it) {
        int idx = tid + it * 256;
        int row = idx >> 5, c = idx & 31;
        float4 v = make_float4(0.f, 0.f, 0.f, 0.f);
        if (n0 + row < NN) v = ((const float4*)(n_embed + (size_t)(n0 + row) * DN))[c];
        unsigned t0 = cvt_pk_bf16(v.x, v.y), t1 = cvt_pk_bf16(v.z, v.w);
        *(uint2*)&s_a[row][c * 4] = make_uint2(t0, t1);
    }
    __syncthreads();

    const int lane = tid & 63, w = tid >> 6;
    const int arow = lane & 15, akb = (lane >> 4) * 8, rbase = (lane >> 4) * 4;

    f32x4 acc[4][3];
    #pragma unroll
    for (int mt = 0; mt < 4; ++mt)
        #pragma unroll
        for (int j = 0; j < 3; ++j) acc[mt][j] = (f32x4){0.f, 0.f, 0.f, 0.f};

    for (int kk = 0; kk < 4; ++kk) {
        bf16x8 a[4], b[3];
        #pragma unroll
        for (int mt = 0; mt < 4; ++mt)
            a[mt] = *(const bf16x8*)&s_a[mt * 16 + arow][kk * 32 + akb];
        #pragma unroll
        for (int j = 0; j < 3; ++j)
            b[j] = *(const bf16x8*)(g_p1 + (((size_t)(kk + 4 * half) * 12 + (3 * w + j)) * 64 + lane) * 8);
        #pragma unroll
        for (int mt = 0; mt < 4; ++mt)
            #pragma unroll
            for (int j = 0; j < 3; ++j)
                acc[mt][j] = __builtin_amdgcn_mfma_f32_16x16x32_bf16(a[mt], b[j], acc[mt][j], 0, 0, 0);
    }

    unsigned short* Pout = P + (size_t)half * NN * DH;
    float bj[3];
    #pragma unroll
    for (int j = 0; j < 3; ++j) bj[j] = (half == 0) ? b1[48 * w + 16 * j + arow] : 0.f;
    const int gq = arow >> 2, ii = arow & 3;
    #pragma unroll
    for (int mt = 0; mt < 4; ++mt)
        #pragma unroll
        for (int j = 0; j < 3; ++j)
            #pragma unroll
            for (int r = 0; r < 4; ++r) {
                int row = n0 + mt * 16 + rbase + r;
                if (row < NN)
                    Pout[((size_t)row * 4 + gq) * 48 + (3 * w + j) * 4 + ii] =
                        f2bf(acc[mt][j][r] + bj[j]);
            }
}

// ---------------------------------------------------------------------------
// edge kernel (GEMM2 folded out): R9 phases 0-1 verbatim, then ONE barrier
// and a per-column segment reduce of h into Hbar (means via invc at flush).
// ---------------------------------------------------------------------------
__global__ __launch_bounds__(256) void edge_reduce(
    const float* __restrict__ e_embed,
    const int* __restrict__ senders, const int* __restrict__ receivers,
    const unsigned short* __restrict__ Ps, const unsigned short* __restrict__ Pr,
    const float* __restrict__ invc, float* __restrict__ Hbar)
{
    __shared__ __align__(16) unsigned short s_h[EB][SHS];  // 25088 B
    __shared__ int s_send[EB];

    const int tid  = threadIdx.x;
    const int nb8  = gridDim.x >> 3;                       // 625
    const int e0   = (((blockIdx.x & 7) * nb8) + (blockIdx.x >> 3)) * EB;  // XCD swizzle
    const int lane = tid & 63, w = tid >> 6;
    const int arow = lane & 15, g = lane >> 4;

    // ---- phase 0: per-lane loads (wide, contiguous per lane) ----
    const int myedge = e0 + w * 16 + arow;
    const int sN = senders[myedge], rN = receivers[myedge];
    const unsigned short* psbase = Ps + ((size_t)sN * 4 + g) * 48;
    const unsigned short* prbase = Pr + ((size_t)rN * 4 + g) * 48;
    uint4 psq[6], prq[6];
    #pragma unroll
    for (int j = 0; j < 6; ++j) {
        psq[j] = *(const uint4*)(psbase + j * 8);
        prq[j] = *(const uint4*)(prbase + j * 8);
    }
    union { bf16x8 v; unsigned u[4]; } bfr;
    {
        const float* erow = e_embed + (size_t)myedge * DE + g * 8;
        float4 ev0 = *(const float4*)erow;
        float4 ev1 = *(const float4*)(erow + 4);
        bfr.u[0] = cvt_pk_bf16(ev0.x, ev0.y);
        bfr.u[1] = cvt_pk_bf16(ev0.z, ev0.w);
        bfr.u[2] = cvt_pk_bf16(ev1.x, ev1.y);
        bfr.u[3] = cvt_pk_bf16(ev1.z, ev1.w);
    }
    if (tid < EB) s_send[tid] = senders[e0 + tid];

    // ---- phase 1: GEMM1^T (12 MFMAs) + P add + tanh -> s_h[edge][hid] ----
    #pragma unroll
    for (int mt = 0; mt < 12; ++mt) {
        unsigned px, py, qx, qy;
        if ((mt & 1) == 0) {
            px = psq[mt >> 1].x; py = psq[mt >> 1].y;
            qx = prq[mt >> 1].x; qy = prq[mt >> 1].y;
        } else {
            px = psq[mt >> 1].z; py = psq[mt >> 1].w;
            qx = prq[mt >> 1].z; qy = prq[mt >> 1].w;
        }
        bf16x8 af = *(const bf16x8*)(g_e + ((size_t)mt * 64 + lane) * 8);
        f32x4 z = (f32x4){0.f, 0.f, 0.f, 0.f};
        f32x4 acc = __builtin_amdgcn_mfma_f32_16x16x32_bf16(af, bfr.v, z, 0, 0, 0);
        float t0 = tanh_fast(acc[0] + bflo(px) + bflo(qx));
        float t1 = tanh_fast(acc[1] + bfhi(px) + bfhi(qx));
        float t2 = tanh_fast(acc[2] + bflo(py) + bflo(qy));
        float t3 = tanh_fast(acc[3] + bfhi(py) + bfhi(qy));
        *(uint2*)&s_h[w * 16 + arow][mt * 16 + g * 4] =
            make_uint2(cvt_pk_bf16(t0, t1), cvt_pk_bf16(t2, t3));
    }
    __syncthreads();

    // ---- phase 2: per-column segment reduce of h (sorted senders) -> Hbar ----
    // thread t owns hid column t; per-instruction the wave reads 64 consecutive
    // b16 (s_h[e][t..t+63]) -> conflict-free.
    if (tid < DH) {
        const int c = tid;
        float sum = 0.f;
        int cur = s_send[0];
        #pragma unroll 8
        for (int e = 0; e < EB; ++e) {
            sum += bf2f(s_h[e][c]);
            int nxt = (e + 1 < EB) ? s_send[e + 1] : -1;
            if (nxt != cur) {
                atomicAdd(&Hbar[(size_t)cur * DH + c], sum * invc[cur]);
                sum = 0.f;
                cur = nxt;
            }
        }
    }
}

// ---------------------------------------------------------------------------
// node_out: out = Hbar(bf16) @ W2 + b2   (each output row written exactly once)
// ---------------------------------------------------------------------------
__global__ __launch_bounds__(256) void node_out(
    const float* __restrict__ Hbar, const float* __restrict__ b2,
    float* __restrict__ out)
{
    __shared__ __align__(16) unsigned short s_a[64][200];  // 25600 B
    const int tid = threadIdx.x;
    const int n0  = blockIdx.x * 64;

    #pragma unroll
    for (int it = 0; it < 12; ++it) {
        int idx = tid + it * 256;           // 64 rows x 48 float4
        int row = idx / 48, c = idx - row * 48;
        float4 v = make_float4(0.f, 0.f, 0.f, 0.f);
        if (n0 + row < NN) v = ((const float4*)(Hbar + (size_t)(n0 + row) * DH))[c];
        unsigned t0 = cvt_pk_bf16(v.x, v.y), t1 = cvt_pk_bf16(v.z, v.w);
        *(uint2*)&s_a[row][c * 4] = make_uint2(t0, t1);
    }
    __syncthreads();

    const int lane = tid & 63, w = tid >> 6;
    const int arow = lane & 15, akb = (lane >> 4) * 8, rbase = (lane >> 4) * 4;

    f32x4 acc[4][2];
    #pragma unroll
    for (int mt = 0; mt < 4; ++mt)
        #pragma unroll
        for (int j = 0; j < 2; ++j) acc[mt][j] = (f32x4){0.f, 0.f, 0.f, 0.f};

    #pragma unroll
    for (int kk = 0; kk < 6; ++kk) {
        bf16x8 a[4], b[2];
        #pragma unroll
        for (int mt = 0; mt < 4; ++mt)
            a[mt] = *(const bf16x8*)&s_a[mt * 16 + arow][kk * 32 + akb];
        #pragma unroll
        for (int j = 0; j < 2; ++j)
            b[j] = *(const bf16x8*)(g_p2 + (((size_t)kk * 8 + (2 * w + j)) * 64 + lane) * 8);
        #pragma unroll
        for (int mt = 0; mt < 4; ++mt)
            #pragma unroll
            for (int j = 0; j < 2; ++j)
                acc[mt][j] = __builtin_amdgcn_mfma_f32_16x16x32_bf16(a[mt], b[j], acc[mt][j], 0, 0, 0);
    }

    const float bd0 = b2[32 * w + arow], bd1 = b2[32 * w + 16 + arow];
    #pragma unroll
    for (int mt = 0; mt < 4; ++mt)
        #pragma unroll
        for (int r = 0; r < 4; ++r) {
            int row = n0 + mt * 16 + rbase + r;
            if (row < NN) {
                out[(size_t)row * DO + 32 * w + arow]      = acc[mt][0][r] + bd0;
                out[(size_t)row * DO + 32 * w + 16 + arow] = acc[mt][1][r] + bd1;
            }
        }
}

extern "C" void kernel_launch(void* const* d_in, const int* in_sizes, int n_in,
                              void* d_out, int out_size, void* d_ws, size_t ws_size,
                              hipStream_t stream)
{
    const float* n_embed   = (const float*)d_in[0];
    const float* e_embed   = (const float*)d_in[1];
    const int*   senders   = (const int*)d_in[2];
    const int*   receivers = (const int*)d_in[3];
    const float* W1        = (const float*)d_in[4];
    const float* b1        = (const float*)d_in[5];
    const float* W2        = (const float*)d_in[6];
    const float* b2        = (const float*)d_in[7];
    float* out = (float*)d_out;

    unsigned short* Ps = (unsigned short*)d_ws;             // [NN][192] bf16 (lane-packed)
    unsigned short* Pr = Ps + (size_t)NN * DH;              // [NN][192] bf16 (lane-packed)
    float*          invc = (float*)(Pr + (size_t)NN * DH);  // [NN] f32
    float*          Hbar = invc + NN;                       // [NN][192] f32

    hipMemsetAsync(Hbar, 0, (size_t)NN * DH * sizeof(float), stream);
    const int prep_items = FRAGS_TOT + NN;
    prep<<<(prep_items + 255) / 256, 256, 0, stream>>>(W1, W2, senders, invc);
    node_proj<<<dim3((NN + 63) / 64, 2), 256, 0, stream>>>(n_embed, b1, Ps);
    edge_reduce<<<E_TOT / EB, 256, 0, stream>>>(
        e_embed, senders, receivers, Ps, Pr, invc, Hbar);
    node_out<<<(NN + 63) / 64, 256, 0, stream>>>(Hbar, b2, out);
}

// Round 14
// 92.258 us; speedup vs baseline: 1.0222x; 1.0181x over previous
//
#include <hip/hip_runtime.h>

#define E_TOT 320000
#define NN    10000
#define DN    128
#define DE    32
#define DH    192
#define DO    128
#define EB    64
#define SHS   196   // s_h row stride in ushorts (392 B)

typedef __attribute__((ext_vector_type(8))) short bf16x8;
typedef __attribute__((ext_vector_type(4))) float f32x4;

// packed weight tables (rewritten every launch)
#define W1_FRAGS (8*12*64)    // node-part B-frags (node_proj)
#define E_FRAGS  (12*64)      // W1_edge^T A-frags (edge GEMM1)
#define W2_FRAGS (6*8*64)     // W2 B-frags (node_out)
#define FRAGS_TOT (W1_FRAGS + E_FRAGS + W2_FRAGS)
__device__ __align__(16) unsigned short g_p1[W1_FRAGS * 8];
__device__ __align__(16) unsigned short g_e [E_FRAGS * 8];
__device__ __align__(16) unsigned short g_p2[W2_FRAGS * 8];

__device__ __forceinline__ unsigned short f2bf(float f) {
    union { float f; unsigned u; } v; v.f = f;
    return (unsigned short)((v.u + 0x7FFFu + ((v.u >> 16) & 1u)) >> 16);
}
__device__ __forceinline__ float bflo(unsigned u) {
    union { unsigned v; float f; } t; t.v = u << 16; return t.f;
}
__device__ __forceinline__ float bfhi(unsigned u) {
    union { unsigned v; float f; } t; t.v = u & 0xFFFF0000u; return t.f;
}
__device__ __forceinline__ float bf2f(unsigned short s) {
    union { unsigned v; float f; } t; t.v = (unsigned)s << 16; return t.f;
}
__device__ __forceinline__ float tanh_fast(float x) {
    float ex = __expf(x + x);
    return 1.0f - 2.0f * __builtin_amdgcn_rcpf(ex + 1.0f);
}
__device__ __forceinline__ unsigned cvt_pk_bf16(float lo, float hi) {
    unsigned r;
    asm("v_cvt_pk_bf16_f32 %0, %1, %2" : "=v"(r) : "v"(lo), "v"(hi));
    return r;
}

// ---------------------------------------------------------------------------
// prep: pack the three weight tables (39 blocks; no cold searches anymore)
// ---------------------------------------------------------------------------
__global__ void prep(const float* __restrict__ W1, const float* __restrict__ W2)
{
    int f = blockIdx.x * 256 + threadIdx.x;
    unsigned short tmp[8];
    if (f < W1_FRAGS) {                       // node-part B-frags: rows 0..255 of W1
        int kk = f / (12 * 64), nt = (f >> 6) % 12, lane = f & 63;
        int r0 = kk * 32 + ((lane >> 4) << 3);
        int c  = nt * 16 + (lane & 15);
        #pragma unroll
        for (int i = 0; i < 8; ++i) tmp[i] = f2bf(W1[(r0 + i) * DH + c]);
        *(uint4*)(g_p1 + (size_t)f * 8) = *(const uint4*)tmp;
    } else if (f < W1_FRAGS + E_FRAGS) {      // W1_edge^T A-frags
        int f2 = f - W1_FRAGS;
        int mt = f2 >> 6, lane = f2 & 63;
        int k0 = ((lane >> 4) << 3);
        int hid = mt * 16 + (lane & 15);
        #pragma unroll
        for (int i = 0; i < 8; ++i) tmp[i] = f2bf(W1[(256 + k0 + i) * DH + hid]);
        *(uint4*)(g_e + (size_t)f2 * 8) = *(const uint4*)tmp;
    } else if (f < FRAGS_TOT) {               // W2 B-frags
        int f3 = f - W1_FRAGS - E_FRAGS;
        int kk = f3 / (8 * 64), nt = (f3 >> 6) % 8, lane = f3 & 63;
        int r0 = kk * 32 + ((lane >> 4) << 3);
        int c  = nt * 16 + (lane & 15);
        #pragma unroll
        for (int i = 0; i < 8; ++i) tmp[i] = f2bf(W2[(r0 + i) * DO + c]);
        *(uint4*)(g_p2 + (size_t)f3 * 8) = *(const uint4*)tmp;
    }
}

// ---------------------------------------------------------------------------
// node projections (lane-contiguous P' layout):
//   P'[n][g][mt][i]: addr = (n*4+g)*48 + mt*4 + i;  original col = mt*16+g*4+i
// ---------------------------------------------------------------------------
__global__ __launch_bounds__(256) void node_proj(
    const float* __restrict__ n_embed, const float* __restrict__ b1,
    unsigned short* __restrict__ P)
{
    __shared__ __align__(16) unsigned short s_a[64][136];
    const int tid  = threadIdx.x;
    const int half = blockIdx.y;
    const int n0   = blockIdx.x * 64;

    #pragma unroll
    for (int it = 0; it < 8; ++it) {
        int idx = tid + it * 256;
        int row = idx >> 5, c = idx & 31;
        float4 v = make_float4(0.f, 0.f, 0.f, 0.f);
        if (n0 + row < NN) v = ((const float4*)(n_embed + (size_t)(n0 + row) * DN))[c];
        unsigned t0 = cvt_pk_bf16(v.x, v.y), t1 = cvt_pk_bf16(v.z, v.w);
        *(uint2*)&s_a[row][c * 4] = make_uint2(t0, t1);
    }
    __syncthreads();

    const int lane = tid & 63, w = tid >> 6;
    const int arow = lane & 15, akb = (lane >> 4) * 8, rbase = (lane >> 4) * 4;

    f32x4 acc[4][3];
    #pragma unroll
    for (int mt = 0; mt < 4; ++mt)
        #pragma unroll
        for (int j = 0; j < 3; ++j) acc[mt][j] = (f32x4){0.f, 0.f, 0.f, 0.f};

    for (int kk = 0; kk < 4; ++kk) {
        bf16x8 a[4], b[3];
        #pragma unroll
        for (int mt = 0; mt < 4; ++mt)
            a[mt] = *(const bf16x8*)&s_a[mt * 16 + arow][kk * 32 + akb];
        #pragma unroll
        for (int j = 0; j < 3; ++j)
            b[j] = *(const bf16x8*)(g_p1 + (((size_t)(kk + 4 * half) * 12 + (3 * w + j)) * 64 + lane) * 8);
        #pragma unroll
        for (int mt = 0; mt < 4; ++mt)
            #pragma unroll
            for (int j = 0; j < 3; ++j)
                acc[mt][j] = __builtin_amdgcn_mfma_f32_16x16x32_bf16(a[mt], b[j], acc[mt][j], 0, 0, 0);
    }

    unsigned short* Pout = P + (size_t)half * NN * DH;
    float bj[3];
    #pragma unroll
    for (int j = 0; j < 3; ++j) bj[j] = (half == 0) ? b1[48 * w + 16 * j + arow] : 0.f;
    const int gq = arow >> 2, ii = arow & 3;
    #pragma unroll
    for (int mt = 0; mt < 4; ++mt)
        #pragma unroll
        for (int j = 0; j < 3; ++j)
            #pragma unroll
            for (int r = 0; r < 4; ++r) {
                int row = n0 + mt * 16 + rbase + r;
                if (row < NN)
                    Pout[((size_t)row * 4 + gq) * 48 + (3 * w + j) * 4 + ii] =
                        f2bf(acc[mt][j][r] + bj[j]);
            }
}

// ---------------------------------------------------------------------------
// edge kernel: gather + GEMM1^T + tanh -> s_h; one barrier; per-column
// segment reduce of h (sorted senders) -> RAW sums into Hbar (atomics).
// ---------------------------------------------------------------------------
__global__ __launch_bounds__(256) void edge_reduce(
    const float* __restrict__ e_embed,
    const int* __restrict__ senders, const int* __restrict__ receivers,
    const unsigned short* __restrict__ Ps, const unsigned short* __restrict__ Pr,
    float* __restrict__ Hbar)
{
    __shared__ __align__(16) unsigned short s_h[EB][SHS];  // 25088 B
    __shared__ int s_send[EB];

    const int tid  = threadIdx.x;
    const int nb8  = gridDim.x >> 3;                       // 625
    const int e0   = (((blockIdx.x & 7) * nb8) + (blockIdx.x >> 3)) * EB;  // XCD swizzle
    const int lane = tid & 63, w = tid >> 6;
    const int arow = lane & 15, g = lane >> 4;

    // ---- phase 0: per-lane loads (wide, contiguous per lane) ----
    const int myedge = e0 + w * 16 + arow;
    const int sN = senders[myedge], rN = receivers[myedge];
    const unsigned short* psbase = Ps + ((size_t)sN * 4 + g) * 48;
    const unsigned short* prbase = Pr + ((size_t)rN * 4 + g) * 48;
    uint4 psq[6], prq[6];
    #pragma unroll
    for (int j = 0; j < 6; ++j) {
        psq[j] = *(const uint4*)(psbase + j * 8);
        prq[j] = *(const uint4*)(prbase + j * 8);
    }
    union { bf16x8 v; unsigned u[4]; } bfr;
    {
        const float* erow = e_embed + (size_t)myedge * DE + g * 8;
        float4 ev0 = *(const float4*)erow;
        float4 ev1 = *(const float4*)(erow + 4);
        bfr.u[0] = cvt_pk_bf16(ev0.x, ev0.y);
        bfr.u[1] = cvt_pk_bf16(ev0.z, ev0.w);
        bfr.u[2] = cvt_pk_bf16(ev1.x, ev1.y);
        bfr.u[3] = cvt_pk_bf16(ev1.z, ev1.w);
    }
    if (tid < EB) s_send[tid] = senders[e0 + tid];

    // ---- phase 1: GEMM1^T (12 MFMAs) + P add + tanh -> s_h[edge][hid] ----
    #pragma unroll
    for (int mt = 0; mt < 12; ++mt) {
        unsigned px, py, qx, qy;
        if ((mt & 1) == 0) {
            px = psq[mt >> 1].x; py = psq[mt >> 1].y;
            qx = prq[mt >> 1].x; qy = prq[mt >> 1].y;
        } else {
            px = psq[mt >> 1].z; py = psq[mt >> 1].w;
            qx = prq[mt >> 1].z; qy = prq[mt >> 1].w;
        }
        bf16x8 af = *(const bf16x8*)(g_e + ((size_t)mt * 64 + lane) * 8);
        f32x4 z = (f32x4){0.f, 0.f, 0.f, 0.f};
        f32x4 acc = __builtin_amdgcn_mfma_f32_16x16x32_bf16(af, bfr.v, z, 0, 0, 0);
        float t0 = tanh_fast(acc[0] + bflo(px) + bflo(qx));
        float t1 = tanh_fast(acc[1] + bfhi(px) + bfhi(qx));
        float t2 = tanh_fast(acc[2] + bflo(py) + bflo(qy));
        float t3 = tanh_fast(acc[3] + bfhi(py) + bfhi(qy));
        *(uint2*)&s_h[w * 16 + arow][mt * 16 + g * 4] =
            make_uint2(cvt_pk_bf16(t0, t1), cvt_pk_bf16(t2, t3));
    }
    __syncthreads();

    // ---- phase 2: per-column segment reduce of h (sorted senders) -> Hbar ----
    if (tid < DH) {
        const int c = tid;
        float sum = 0.f;
        int cur = s_send[0];
        #pragma unroll 8
        for (int e = 0; e < EB; ++e) {
            sum += bf2f(s_h[e][c]);
            int nxt = (e + 1 < EB) ? s_send[e + 1] : -1;
            if (nxt != cur) {
                atomicAdd(&Hbar[(size_t)cur * DH + c], sum);
                sum = 0.f;
                cur = nxt;
            }
        }
    }
}

// ---------------------------------------------------------------------------
// node_out v2: one INDEPENDENT wave per 16 output rows; no LDS, no barrier.
//   out = (Hbar * invc) @ W2 + b2, invc computed in-wave (senders L2-warm).
// ---------------------------------------------------------------------------
__global__ __launch_bounds__(256) void node_out(
    const float* __restrict__ Hbar, const int* __restrict__ senders,
    const float* __restrict__ b2, float* __restrict__ out)
{
    const int tid  = threadIdx.x;
    const int lane = tid & 63, w = tid >> 6;
    const int n0   = (blockIdx.x * 4 + w) * 16;
    if (n0 >= NN) return;
    const int arow = lane & 15, akb = (lane >> 4) * 8, rbase = (lane >> 4) * 4;

    // my A-row and its 1/count (clamped; garbage rows masked at store)
    const int myrow = (n0 + arow < NN) ? (n0 + arow) : (NN - 1);
    float ic;
    {
        int lo = 0, hi = E_TOT;
        while (lo < hi) { int m = (lo + hi) >> 1; if (senders[m] < myrow) lo = m + 1; else hi = m; }
        int s0 = lo;
        hi = E_TOT;
        while (lo < hi) { int m = (lo + hi) >> 1; if (senders[m] < myrow + 1) lo = m + 1; else hi = m; }
        int cnt = lo - s0;
        ic = (cnt > 0) ? 1.0f / (float)cnt : 0.0f;
    }

    // A-frags: Hbar[myrow][kk*32+akb .. +8] * ic  -> bf16
    const float* hrow = Hbar + (size_t)myrow * DH;
    union { bf16x8 v; unsigned u[4]; } a[6];
    #pragma unroll
    for (int kk = 0; kk < 6; ++kk) {
        float4 v0 = *(const float4*)(hrow + kk * 32 + akb);
        float4 v1 = *(const float4*)(hrow + kk * 32 + akb + 4);
        a[kk].u[0] = cvt_pk_bf16(v0.x * ic, v0.y * ic);
        a[kk].u[1] = cvt_pk_bf16(v0.z * ic, v0.w * ic);
        a[kk].u[2] = cvt_pk_bf16(v1.x * ic, v1.y * ic);
        a[kk].u[3] = cvt_pk_bf16(v1.z * ic, v1.w * ic);
    }

    f32x4 acc[8];
    #pragma unroll
    for (int j = 0; j < 8; ++j) acc[j] = (f32x4){0.f, 0.f, 0.f, 0.f};

    #pragma unroll
    for (int kk = 0; kk < 6; ++kk)
        #pragma unroll
        for (int j = 0; j < 8; ++j) {
            bf16x8 b = *(const bf16x8*)(g_p2 + (((size_t)kk * 8 + j) * 64 + lane) * 8);
            acc[j] = __builtin_amdgcn_mfma_f32_16x16x32_bf16(a[kk].v, b, acc[j], 0, 0, 0);
        }

    #pragma unroll
    for (int j = 0; j < 8; ++j) {
        const float bd = b2[j * 16 + arow];
        #pragma unroll
        for (int r = 0; r < 4; ++r) {
            int row = n0 + rbase + r;
            if (row < NN)
                out[(size_t)row * DO + j * 16 + arow] = acc[j][r] + bd;
        }
    }
}

extern "C" void kernel_launch(void* const* d_in, const int* in_sizes, int n_in,
                              void* d_out, int out_size, void* d_ws, size_t ws_size,
                              hipStream_t stream)
{
    const float* n_embed   = (const float*)d_in[0];
    const float* e_embed   = (const float*)d_in[1];
    const int*   senders   = (const int*)d_in[2];
    const int*   receivers = (const int*)d_in[3];
    const float* W1        = (const float*)d_in[4];
    const float* b1        = (const float*)d_in[5];
    const float* W2        = (const float*)d_in[6];
    const float* b2        = (const float*)d_in[7];
    float* out = (float*)d_out;

    unsigned short* Ps = (unsigned short*)d_ws;             // [NN][192] bf16 (lane-packed)
    unsigned short* Pr = Ps + (size_t)NN * DH;              // [NN][192] bf16 (lane-packed)
    float*          Hbar = (float*)(Pr + (size_t)NN * DH);  // [NN][192] f32

    hipMemsetAsync(Hbar, 0, (size_t)NN * DH * sizeof(float), stream);
    prep<<<(FRAGS_TOT + 255) / 256, 256, 0, stream>>>(W1, W2);
    node_proj<<<dim3((NN + 63) / 64, 2), 256, 0, stream>>>(n_embed, b1, Ps);
    edge_reduce<<<E_TOT / EB, 256, 0, stream>>>(
        e_embed, senders, receivers, Ps, Pr, Hbar);
    node_out<<<(NN + 63) / 64, 256, 0, stream>>>(Hbar, senders, b2, out);
}

// Round 15
// 79.230 us; speedup vs baseline: 1.1903x; 1.1644x over previous
//
#include <hip/hip_runtime.h>

#define E_TOT 320000
#define NN    10000
#define DN    128
#define DE    32
#define DH    192
#define DO    128
#define EB    64
#define SHS   196   // s_h row stride in ushorts (392 B)

typedef __attribute__((ext_vector_type(8))) short bf16x8;
typedef __attribute__((ext_vector_type(4))) float f32x4;

// packed weight tables (rewritten every launch)
#define W1_FRAGS (8*12*64)    // node-part B-frags (node_proj)
#define E_FRAGS  (12*64)      // W1_edge^T A-frags (edge GEMM1)
#define W2_FRAGS (6*8*64)     // W2 B-frags (node_out)
#define FRAGS_TOT (W1_FRAGS + E_FRAGS + W2_FRAGS)
#define ZH (NN * DH / 4)      // Hbar zero items (float4)
__device__ __align__(16) unsigned short g_p1[W1_FRAGS * 8];
__device__ __align__(16) unsigned short g_e [E_FRAGS * 8];
__device__ __align__(16) unsigned short g_p2[W2_FRAGS * 8];

__device__ __forceinline__ unsigned short f2bf(float f) {
    union { float f; unsigned u; } v; v.f = f;
    return (unsigned short)((v.u + 0x7FFFu + ((v.u >> 16) & 1u)) >> 16);
}
__device__ __forceinline__ float bflo(unsigned u) {
    union { unsigned v; float f; } t; t.v = u << 16; return t.f;
}
__device__ __forceinline__ float bfhi(unsigned u) {
    union { unsigned v; float f; } t; t.v = u & 0xFFFF0000u; return t.f;
}
__device__ __forceinline__ float bf2f(unsigned short s) {
    union { unsigned v; float f; } t; t.v = (unsigned)s << 16; return t.f;
}
__device__ __forceinline__ float tanh_fast(float x) {
    float ex = __expf(x + x);
    return 1.0f - 2.0f * __builtin_amdgcn_rcpf(ex + 1.0f);
}
__device__ __forceinline__ unsigned cvt_pk_bf16(float lo, float hi) {
    unsigned r;
    asm("v_cvt_pk_bf16_f32 %0, %1, %2" : "=v"(r) : "v"(lo), "v"(hi));
    return r;
}

// ---------------------------------------------------------------------------
// prep: pack weight tables + zero Hbar + build row_start[0..NN]
//   row_start[n] = lower_bound(senders, n); built by boundary detection.
// ---------------------------------------------------------------------------
__global__ void prep(const float* __restrict__ W1, const float* __restrict__ W2,
                     const int* __restrict__ senders,
                     float* __restrict__ Hbar, int* __restrict__ row_start)
{
    int f = blockIdx.x * 256 + threadIdx.x;
    unsigned short tmp[8];
    if (f < W1_FRAGS) {                       // node-part B-frags: rows 0..255 of W1
        int kk = f / (12 * 64), nt = (f >> 6) % 12, lane = f & 63;
        int r0 = kk * 32 + ((lane >> 4) << 3);
        int c  = nt * 16 + (lane & 15);
        #pragma unroll
        for (int i = 0; i < 8; ++i) tmp[i] = f2bf(W1[(r0 + i) * DH + c]);
        *(uint4*)(g_p1 + (size_t)f * 8) = *(const uint4*)tmp;
    } else if (f < W1_FRAGS + E_FRAGS) {      // W1_edge^T A-frags
        int f2 = f - W1_FRAGS;
        int mt = f2 >> 6, lane = f2 & 63;
        int k0 = ((lane >> 4) << 3);
        int hid = mt * 16 + (lane & 15);
        #pragma unroll
        for (int i = 0; i < 8; ++i) tmp[i] = f2bf(W1[(256 + k0 + i) * DH + hid]);
        *(uint4*)(g_e + (size_t)f2 * 8) = *(const uint4*)tmp;
    } else if (f < FRAGS_TOT) {               // W2 B-frags
        int f3 = f - W1_FRAGS - E_FRAGS;
        int kk = f3 / (8 * 64), nt = (f3 >> 6) % 8, lane = f3 & 63;
        int r0 = kk * 32 + ((lane >> 4) << 3);
        int c  = nt * 16 + (lane & 15);
        #pragma unroll
        for (int i = 0; i < 8; ++i) tmp[i] = f2bf(W2[(r0 + i) * DO + c]);
        *(uint4*)(g_p2 + (size_t)f3 * 8) = *(const uint4*)tmp;
    } else if (f < FRAGS_TOT + ZH) {          // zero Hbar (float4)
        ((float4*)Hbar)[f - FRAGS_TOT] = make_float4(0.f, 0.f, 0.f, 0.f);
    } else if (f < FRAGS_TOT + ZH + E_TOT) {  // row_start builder
        int e = f - FRAGS_TOT - ZH;
        int s_cur  = senders[e];
        int s_prev = (e == 0) ? -1 : senders[e - 1];
        if (s_prev != s_cur)
            for (int n = s_prev + 1; n <= s_cur; ++n) row_start[n] = e;
        if (e == E_TOT - 1)
            for (int n = s_cur + 1; n <= NN; ++n) row_start[n] = E_TOT;
    }
}

// ---------------------------------------------------------------------------
// node projections (lane-contiguous P' layout):
//   P'[n][g][mt][i]: addr = (n*4+g)*48 + mt*4 + i;  original col = mt*16+g*4+i
// ---------------------------------------------------------------------------
__global__ __launch_bounds__(256) void node_proj(
    const float* __restrict__ n_embed, const float* __restrict__ b1,
    unsigned short* __restrict__ P)
{
    __shared__ __align__(16) unsigned short s_a[64][136];
    const int tid  = threadIdx.x;
    const int half = blockIdx.y;
    const int n0   = blockIdx.x * 64;

    #pragma unroll
    for (int it = 0; it < 8; ++it) {
        int idx = tid + it * 256;
        int row = idx >> 5, c = idx & 31;
        float4 v = make_float4(0.f, 0.f, 0.f, 0.f);
        if (n0 + row < NN) v = ((const float4*)(n_embed + (size_t)(n0 + row) * DN))[c];
        unsigned t0 = cvt_pk_bf16(v.x, v.y), t1 = cvt_pk_bf16(v.z, v.w);
        *(uint2*)&s_a[row][c * 4] = make_uint2(t0, t1);
    }
    __syncthreads();

    const int lane = tid & 63, w = tid >> 6;
    const int arow = lane & 15, akb = (lane >> 4) * 8, rbase = (lane >> 4) * 4;

    f32x4 acc[4][3];
    #pragma unroll
    for (int mt = 0; mt < 4; ++mt)
        #pragma unroll
        for (int j = 0; j < 3; ++j) acc[mt][j] = (f32x4){0.f, 0.f, 0.f, 0.f};

    for (int kk = 0; kk < 4; ++kk) {
        bf16x8 a[4], b[3];
        #pragma unroll
        for (int mt = 0; mt < 4; ++mt)
            a[mt] = *(const bf16x8*)&s_a[mt * 16 + arow][kk * 32 + akb];
        #pragma unroll
        for (int j = 0; j < 3; ++j)
            b[j] = *(const bf16x8*)(g_p1 + (((size_t)(kk + 4 * half) * 12 + (3 * w + j)) * 64 + lane) * 8);
        #pragma unroll
        for (int mt = 0; mt < 4; ++mt)
            #pragma unroll
            for (int j = 0; j < 3; ++j)
                acc[mt][j] = __builtin_amdgcn_mfma_f32_16x16x32_bf16(a[mt], b[j], acc[mt][j], 0, 0, 0);
    }

    unsigned short* Pout = P + (size_t)half * NN * DH;
    float bj[3];
    #pragma unroll
    for (int j = 0; j < 3; ++j) bj[j] = (half == 0) ? b1[48 * w + 16 * j + arow] : 0.f;
    const int gq = arow >> 2, ii = arow & 3;
    #pragma unroll
    for (int mt = 0; mt < 4; ++mt)
        #pragma unroll
        for (int j = 0; j < 3; ++j)
            #pragma unroll
            for (int r = 0; r < 4; ++r) {
                int row = n0 + mt * 16 + rbase + r;
                if (row < NN)
                    Pout[((size_t)row * 4 + gq) * 48 + (3 * w + j) * 4 + ii] =
                        f2bf(acc[mt][j][r] + bj[j]);
            }
}

// ---------------------------------------------------------------------------
// edge kernel: gather + GEMM1^T (P-add folded into MFMA C-input) + tanh ->
// s_h; one barrier; per-column segment reduce -> RAW sums into Hbar.
// ---------------------------------------------------------------------------
__global__ __launch_bounds__(256) void edge_reduce(
    const float* __restrict__ e_embed,
    const int* __restrict__ senders, const int* __restrict__ receivers,
    const unsigned short* __restrict__ Ps, const unsigned short* __restrict__ Pr,
    float* __restrict__ Hbar)
{
    __shared__ __align__(16) unsigned short s_h[EB][SHS];  // 25088 B
    __shared__ int s_send[EB];

    const int tid  = threadIdx.x;
    const int nb8  = gridDim.x >> 3;                       // 625
    const int e0   = (((blockIdx.x & 7) * nb8) + (blockIdx.x >> 3)) * EB;  // XCD swizzle
    const int lane = tid & 63, w = tid >> 6;
    const int arow = lane & 15, g = lane >> 4;

    // ---- phase 0: per-lane loads (wide, contiguous per lane) ----
    const int myedge = e0 + w * 16 + arow;
    const int sN = senders[myedge], rN = receivers[myedge];
    const unsigned short* psbase = Ps + ((size_t)sN * 4 + g) * 48;
    const unsigned short* prbase = Pr + ((size_t)rN * 4 + g) * 48;
    uint4 psq[6], prq[6];
    #pragma unroll
    for (int j = 0; j < 6; ++j) {
        psq[j] = *(const uint4*)(psbase + j * 8);
        prq[j] = *(const uint4*)(prbase + j * 8);
    }
    union { bf16x8 v; unsigned u[4]; } bfr;
    {
        const float* erow = e_embed + (size_t)myedge * DE + g * 8;
        float4 ev0 = *(const float4*)erow;
        float4 ev1 = *(const float4*)(erow + 4);
        bfr.u[0] = cvt_pk_bf16(ev0.x, ev0.y);
        bfr.u[1] = cvt_pk_bf16(ev0.z, ev0.w);
        bfr.u[2] = cvt_pk_bf16(ev1.x, ev1.y);
        bfr.u[3] = cvt_pk_bf16(ev1.z, ev1.w);
    }
    if (tid < EB) s_send[tid] = senders[e0 + tid];

    // ---- phase 1: GEMM1^T, C-input = Ps+Pr; tanh -> s_h[edge][hid] ----
    #pragma unroll
    for (int mt = 0; mt < 12; ++mt) {
        unsigned px, py, qx, qy;
        if ((mt & 1) == 0) {
            px = psq[mt >> 1].x; py = psq[mt >> 1].y;
            qx = prq[mt >> 1].x; qy = prq[mt >> 1].y;
        } else {
            px = psq[mt >> 1].z; py = psq[mt >> 1].w;
            qx = prq[mt >> 1].z; qy = prq[mt >> 1].w;
        }
        f32x4 cinit;
        cinit[0] = bflo(px) + bflo(qx);
        cinit[1] = bfhi(px) + bfhi(qx);
        cinit[2] = bflo(py) + bflo(qy);
        cinit[3] = bfhi(py) + bfhi(qy);
        bf16x8 af = *(const bf16x8*)(g_e + ((size_t)mt * 64 + lane) * 8);
        f32x4 acc = __builtin_amdgcn_mfma_f32_16x16x32_bf16(af, bfr.v, cinit, 0, 0, 0);
        float t0 = tanh_fast(acc[0]);
        float t1 = tanh_fast(acc[1]);
        float t2 = tanh_fast(acc[2]);
        float t3 = tanh_fast(acc[3]);
        *(uint2*)&s_h[w * 16 + arow][mt * 16 + g * 4] =
            make_uint2(cvt_pk_bf16(t0, t1), cvt_pk_bf16(t2, t3));
    }
    __syncthreads();

    // ---- phase 2: per-column segment reduce of h (sorted senders) -> Hbar ----
    if (tid < DH) {
        const int c = tid;
        float sum = 0.f;
        int cur = s_send[0];
        #pragma unroll 8
        for (int e = 0; e < EB; ++e) {
            sum += bf2f(s_h[e][c]);
            int nxt = (e + 1 < EB) ? s_send[e + 1] : -1;
            if (nxt != cur) {
                atomicAdd(&Hbar[(size_t)cur * DH + c], sum);
                sum = 0.f;
                cur = nxt;
            }
        }
    }
}

// ---------------------------------------------------------------------------
// node_out v3: one independent wave per 16 rows; counts from row_start
// (2 coalesced loads, no binary search).  out = (Hbar*invc) @ W2 + b2.
// ---------------------------------------------------------------------------
__global__ __launch_bounds__(256) void node_out(
    const float* __restrict__ Hbar, const int* __restrict__ row_start,
    const float* __restrict__ b2, float* __restrict__ out)
{
    const int tid  = threadIdx.x;
    const int lane = tid & 63, w = tid >> 6;
    const int n0   = (blockIdx.x * 4 + w) * 16;
    if (n0 >= NN) return;
    const int arow = lane & 15, akb = (lane >> 4) * 8, rbase = (lane >> 4) * 4;

    const int myrow = (n0 + arow < NN) ? (n0 + arow) : (NN - 1);
    const int cnt = row_start[myrow + 1] - row_start[myrow];
    const float ic = (cnt > 0) ? 1.0f / (float)cnt : 0.0f;

    const float* hrow = Hbar + (size_t)myrow * DH;
    union { bf16x8 v; unsigned u[4]; } a[6];
    #pragma unroll
    for (int kk = 0; kk < 6; ++kk) {
        float4 v0 = *(const float4*)(hrow + kk * 32 + akb);
        float4 v1 = *(const float4*)(hrow + kk * 32 + akb + 4);
        a[kk].u[0] = cvt_pk_bf16(v0.x * ic, v0.y * ic);
        a[kk].u[1] = cvt_pk_bf16(v0.z * ic, v0.w * ic);
        a[kk].u[2] = cvt_pk_bf16(v1.x * ic, v1.y * ic);
        a[kk].u[3] = cvt_pk_bf16(v1.z * ic, v1.w * ic);
    }

    f32x4 acc[8];
    #pragma unroll
    for (int j = 0; j < 8; ++j) acc[j] = (f32x4){0.f, 0.f, 0.f, 0.f};

    #pragma unroll
    for (int kk = 0; kk < 6; ++kk)
        #pragma unroll
        for (int j = 0; j < 8; ++j) {
            bf16x8 b = *(const bf16x8*)(g_p2 + (((size_t)kk * 8 + j) * 64 + lane) * 8);
            acc[j] = __builtin_amdgcn_mfma_f32_16x16x32_bf16(a[kk].v, b, acc[j], 0, 0, 0);
        }

    #pragma unroll
    for (int j = 0; j < 8; ++j) {
        const float bd = b2[j * 16 + arow];
        #pragma unroll
        for (int r = 0; r < 4; ++r) {
            int row = n0 + rbase + r;
            if (row < NN)
                out[(size_t)row * DO + j * 16 + arow] = acc[j][r] + bd;
        }
    }
}

extern "C" void kernel_launch(void* const* d_in, const int* in_sizes, int n_in,
                              void* d_out, int out_size, void* d_ws, size_t ws_size,
                              hipStream_t stream)
{
    const float* n_embed   = (const float*)d_in[0];
    const float* e_embed   = (const float*)d_in[1];
    const int*   senders   = (const int*)d_in[2];
    const int*   receivers = (const int*)d_in[3];
    const float* W1        = (const float*)d_in[4];
    const float* b1        = (const float*)d_in[5];
    const float* W2        = (const float*)d_in[6];
    const float* b2        = (const float*)d_in[7];
    float* out = (float*)d_out;

    unsigned short* Ps   = (unsigned short*)d_ws;             // [NN][192] bf16 (lane-packed)
    unsigned short* Pr   = Ps + (size_t)NN * DH;              // [NN][192] bf16 (lane-packed)
    float*          Hbar = (float*)(Pr + (size_t)NN * DH);    // [NN][192] f32
    int*            row_start = (int*)(Hbar + (size_t)NN * DH);  // [NN+1]

    const int prep_items = FRAGS_TOT + ZH + E_TOT;
    prep<<<(prep_items + 255) / 256, 256, 0, stream>>>(W1, W2, senders, Hbar, row_start);
    node_proj<<<dim3((NN + 63) / 64, 2), 256, 0, stream>>>(n_embed, b1, Ps);
    edge_reduce<<<E_TOT / EB, 256, 0, stream>>>(
        e_embed, senders, receivers, Ps, Pr, Hbar);
    node_out<<<(NN + 63) / 64, 256, 0, stream>>>(Hbar, row_start, b2, out);
}